// Round 14
// baseline (192.529 us; speedup 1.0000x reference)
//
#include <hip/hip_runtime.h>
#include <hip/hip_bf16.h>
#include <math.h>

#define BB 8
#define SS 2048
#define HH 8
#define DM 512
#define DK 64

typedef short bf16x8 __attribute__((ext_vector_type(8)));
typedef float f32x4 __attribute__((ext_vector_type(4)));

static __device__ __forceinline__ short f2bf(float f) {
    union { __hip_bfloat16 h; short s; } u;
    u.h = __float2bfloat16(f);
    return u.s;
}

// exp2 (v_exp_f32); Q pre-scaled by 0.125*log2e so 2^s == e^(s/8)
static __device__ __forceinline__ float fexp2(float x) {
#if __has_builtin(__builtin_amdgcn_exp2f)
    return __builtin_amdgcn_exp2f(x);
#else
    return __expf(x * 0.69314718056f);
#endif
}

// async 16B global->LDS; LDS dest wave-uniform base + lane*16 implicit
static __device__ __forceinline__ void gld16(void* lds, const void* g) {
    __builtin_amdgcn_global_load_lds((const __attribute__((address_space(1))) void*)g,
                                     (__attribute__((address_space(3))) void*)lds, 16, 0, 0);
}

// swizzled read of 8 shorts from a [rows][64]-short LDS tile: 16B slot ^= (row&7)
static __device__ __forceinline__ bf16x8 fragRow(const short* lds, int row, int cshort) {
    return *(const bf16x8*)(lds + row * 64 + (cshort ^ ((row & 7) << 3)));
}

// raw barrier + scheduler fence (prevents ds ops drifting across the barrier)
static __device__ __forceinline__ void bar() {
    __builtin_amdgcn_s_barrier();
    __builtin_amdgcn_sched_barrier(0);
}
#define WAITV4 asm volatile("s_waitcnt vmcnt(4)" ::: "memory")
#define WAITV2 asm volatile("s_waitcnt vmcnt(2)" ::: "memory")
#define WAITV0 asm volatile("s_waitcnt vmcnt(0)" ::: "memory")
#define WAITL0 asm volatile("s_waitcnt lgkmcnt(0)" ::: "memory")
#define SCHED0 __builtin_amdgcn_sched_barrier(0)

// ---------------- merged transpose-convert: Wq/Wk/Wv (z<24) and Wo (z in [24,32)) ----------------
__global__ __launch_bounds__(256) void tcvtAll(const float* __restrict__ Wq, const float* __restrict__ Wk,
                                               const float* __restrict__ Wv, const float* __restrict__ Wo,
                                               short* __restrict__ WqT, short* __restrict__ WkT,
                                               short* __restrict__ WvT, short* __restrict__ WoT) {
    __shared__ short T[64][72];
    const int z = blockIdx.z;
    const int t = threadIdx.x;
    const int r0 = blockIdx.x * 64;
    const float* src;
    short* dst;
    int C, R, c0;
    if (z < 24) {
        const int which = z >> 3, h = z & 7;
        src = (which == 0 ? Wq : (which == 1 ? Wk : Wv)) + (size_t)h * DM * DK;
        dst = (which == 0 ? WqT : (which == 1 ? WkT : WvT)) + (size_t)h * DK * DM;
        C = DK; R = DM; c0 = 0;
    } else {
        src = Wo; dst = WoT;
        C = DM; R = DM; c0 = (z - 24) * 64;
    }
#pragma unroll
    for (int p = 0; p < 4; ++p) {
        int idx = t + 256 * p;
        int row = idx >> 4, c4 = (idx & 15) * 4;
        float4 v = *(const float4*)(src + (size_t)(r0 + row) * C + c0 + c4);
        T[c4 + 0][row] = f2bf(v.x);
        T[c4 + 1][row] = f2bf(v.y);
        T[c4 + 2][row] = f2bf(v.z);
        T[c4 + 3][row] = f2bf(v.w);
    }
    __syncthreads();
#pragma unroll
    for (int p = 0; p < 2; ++p) {
        int idx = t + 256 * p;
        int row = idx >> 3, slot = idx & 7;
        *(bf16x8*)(dst + (size_t)(c0 + row) * R + r0 + slot * 8) = *(const bf16x8*)&T[row][slot * 8];
    }
}

// ---------------- merged Q/K/V projection: fp32 X (reg-staged+cvt) @ bf16 WT ----------------
// Single-As-buffer T14 split; LDS 32 KB. launch_bounds (256,4): VGPR cap 128 fits the
// ~68-reg live set — (256,5)'s ~102 cap spilled ra[] to scratch (R9: 300MB writes).
__global__ __launch_bounds__(256, 4) void proj_mfma(const float* __restrict__ qX,
                                                    const float* __restrict__ kX,
                                                    const float* __restrict__ vX,
                                                    const short* __restrict__ WqT,
                                                    const short* __restrict__ WkT,
                                                    const short* __restrict__ WvT,
                                                    const float* __restrict__ bq,
                                                    const float* __restrict__ bk,
                                                    const float* __restrict__ bv,
                                                    short* __restrict__ qY,
                                                    short* __restrict__ kY,
                                                    short* __restrict__ vY,
                                                    float qscale) {
    __shared__ short As[128 * 64];     // 16 KB, single buffer
    __shared__ short Bs[2][64 * 64];   // 16 KB dbuf
    const int mode = blockIdx.y;
    const float* X = mode == 0 ? qX : (mode == 1 ? kX : vX);
    const short* WT = mode == 0 ? WqT : (mode == 1 ? WkT : WvT);
    const float* bias = mode == 0 ? bq : (mode == 1 ? bk : bv);
    short* Y = mode == 0 ? qY : (mode == 1 ? kY : vY);
    const float scale = mode == 0 ? qscale : 1.0f;

    const int lin = blockIdx.x;
    const int b = lin & 7, h = (lin >> 3) & 7;      // same-b blocks share an XCD's L2
    const int s0 = (lin >> 6) * 128;
    const int bh = b * 8 + h;
    const int t = threadIdx.x;
    const int l = t & 63, w = t >> 6;
    const int lr = l & 15, g = l >> 4;
    const float* Xb = X + ((size_t)b * SS + s0) * DM;
    const short* Wh = WT + (size_t)h * DK * DM;
    f32x4 acc[2][4];
#pragma unroll
    for (int i = 0; i < 2; ++i)
#pragma unroll
        for (int j = 0; j < 4; ++j) acc[i][j] = (f32x4){0.f, 0.f, 0.f, 0.f};

    float4 ra[8];
    auto loadA = [&](int k0) {
#pragma unroll
        for (int p = 0; p < 4; ++p) {
            int c = p * 256 + t;
            int row = c >> 3, col = (c & 7) * 8;
            ra[2 * p]     = *(const float4*)(Xb + (size_t)row * DM + k0 + col);
            ra[2 * p + 1] = *(const float4*)(Xb + (size_t)row * DM + k0 + col + 4);
        }
    };
    auto writeA = [&]() {
#pragma unroll
        for (int p = 0; p < 4; ++p) {
            int c = p * 256 + t;
            int row = c >> 3, slot = c & 7;
            bf16x8 o;
            o[0] = f2bf(ra[2 * p].x); o[1] = f2bf(ra[2 * p].y);
            o[2] = f2bf(ra[2 * p].z); o[3] = f2bf(ra[2 * p].w);
            o[4] = f2bf(ra[2 * p + 1].x); o[5] = f2bf(ra[2 * p + 1].y);
            o[6] = f2bf(ra[2 * p + 1].z); o[7] = f2bf(ra[2 * p + 1].w);
            *(bf16x8*)(As + row * 64 + ((slot ^ (row & 7)) * 8)) = o;
        }
    };
    auto stageB = [&](int buf, int k0) {
#pragma unroll
        for (int p = 0; p < 2; ++p) {
            int c = p * 256 + w * 64 + l;
            int row = c >> 3, slot = c & 7;
            gld16(Bs[buf] + (size_t)(p * 256 + w * 64) * 8,
                  Wh + (size_t)row * DM + k0 + ((slot ^ (row & 7)) * 8));
        }
    };

    loadA(0);            // oldest in queue
    stageB(0, 0);        // newest
    writeA();            // compiler waits vmcnt for ra only (B stays in flight)
    __syncthreads();     // drains vmcnt0 + lgkm, As/B0 visible
    int cur = 0;
    for (int k0 = 0; k0 < DM; k0 += 64) {
        const bool next = (k0 + 64 < DM);
        if (next) { loadA(k0 + 64); stageB(cur ^ 1, k0 + 64); }   // issue early (T14)
        SCHED0;
        bf16x8 bfr[4][2];
#pragma unroll
        for (int bf = 0; bf < 4; ++bf) {
            bfr[bf][0] = fragRow(Bs[cur], 16 * bf + lr, 8 * g);
            bfr[bf][1] = fragRow(Bs[cur], 16 * bf + lr, 32 + 8 * g);
        }
#pragma unroll
        for (int af = 0; af < 2; ++af) {
            bf16x8 a0 = fragRow(As, 32 * w + 16 * af + lr, 8 * g);
            bf16x8 a1 = fragRow(As, 32 * w + 16 * af + lr, 32 + 8 * g);
#pragma unroll
            for (int bf = 0; bf < 4; ++bf) {
                acc[af][bf] = __builtin_amdgcn_mfma_f32_16x16x32_bf16(a0, bfr[bf][0], acc[af][bf], 0, 0, 0);
                acc[af][bf] = __builtin_amdgcn_mfma_f32_16x16x32_bf16(a1, bfr[bf][1], acc[af][bf], 0, 0, 0);
            }
        }
        if (next) {
            bar();          // all waves finished READING As (ds_reads already waited)
            writeA();       // overwrite As with next tile (vmcnt wait leaves B in flight)
            __syncthreads();// drain vmcnt0+lgkm: As + Bs[cur^1] ready
        }
        cur ^= 1;
    }
    if (mode == 2) {
        // V^T with within-32 k-permutation: offset 16qf+4g+r stored at 8g+4qf+r
        short* Yb = Y + (size_t)bh * DK * SS;
#pragma unroll
        for (int qf = 0; qf < 2; ++qf)
#pragma unroll
            for (int nf = 0; nf < 4; ++nf) {
                int n = 16 * nf + lr;
                float bv2 = bias[h * DK + n];
                short4 o;
                o.x = f2bf(acc[qf][nf][0] + bv2);
                o.y = f2bf(acc[qf][nf][1] + bv2);
                o.z = f2bf(acc[qf][nf][2] + bv2);
                o.w = f2bf(acc[qf][nf][3] + bv2);
                *(short4*)(Yb + (size_t)n * SS + s0 + 32 * w + 8 * g + 4 * qf) = o;
            }
    } else {
        short* Yb = Y + ((size_t)bh * SS + s0) * DK;
#pragma unroll
        for (int qf = 0; qf < 2; ++qf)
#pragma unroll
            for (int nf = 0; nf < 4; ++nf) {
                int n = 16 * nf + lr;
                float bv2 = bias[h * DK + n];
#pragma unroll
                for (int r = 0; r < 4; ++r)
                    Yb[(size_t)(32 * w + 16 * qf + 4 * g + r) * DK + n] =
                        f2bf((acc[qf][nf][r] + bv2) * scale);
            }
    }
}

// ---------------- stats: z[k] = sum_q 2^s'; LDS union (K staged, bk hoisted, region -> Q bufs) ----------------
__global__ __launch_bounds__(256, 4) void stats_mfma(const short* __restrict__ qs,
                                                     const short* __restrict__ kh,
                                                     float* __restrict__ izOut) {
    __shared__ short LDS[16384];       // 32 KB: K tile first, then 4x 8KB Q buffers
    const int bid = blockIdx.x;
    const int r = bid & 63;
    const int bh = ((r & 7) << 3) | (r >> 3);   // same-bh blocks share an XCD
    const int k0 = (bid >> 6) * 256;
    const int t = threadIdx.x;
    const int l = t & 63, w = t >> 6;
    const int lr = l & 15, g = l >> 4;
    const short* Qb = qs + (size_t)bh * SS * DK;
    const short* Kb = kh + ((size_t)bh * SS + k0) * DK;

    // stage K tile [256][64] into the full region
#pragma unroll
    for (int p = 0; p < 8; ++p) {
        int c = p * 256 + w * 64 + l;
        int row = c >> 3, slot = c & 7;
        gld16(LDS + (size_t)(p * 256 + w * 64) * 8,
              Kb + (size_t)row * DK + ((slot ^ (row & 7)) * 8));
    }
    WAITV0;
    bar();
    bf16x8 bk[4][2];                   // hoist wave's 64 k-cols to registers
#pragma unroll
    for (int c2 = 0; c2 < 4; ++c2) {
        bk[c2][0] = fragRow(LDS, 64 * w + 16 * c2 + lr, 8 * g);
        bk[c2][1] = fragRow(LDS, 64 * w + 16 * c2 + lr, 32 + 8 * g);
    }
    WAITL0;
    SCHED0;
    bar();                             // K region now recyclable as Q buffers

    auto stageQ = [&](int buf, int qq) {
#pragma unroll
        for (int p = 0; p < 2; ++p) {
            int c = p * 256 + w * 64 + l;
            int row = c >> 3, slot = c & 7;
            gld16(LDS + buf * 4096 + (size_t)(p * 256 + w * 64) * 8,
                  Qb + (size_t)(qq + row) * DK + ((slot ^ (row & 7)) * 8));
        }
    };
    stageQ(0, 0);
    stageQ(1, 64);
    WAITV2;
    bar();

    f32x4 zacc[4];
#pragma unroll
    for (int c2 = 0; c2 < 4; ++c2) zacc[c2] = (f32x4){0.f, 0.f, 0.f, 0.f};

    int cur = 0;
    for (int it = 0; it < 32; ++it) {
        const bool pre = (it < 30);
        if (pre) stageQ((cur + 2) & 3, (it + 2) * 64);
        const short* Qcur = LDS + cur * 4096;
        __builtin_amdgcn_s_setprio(1);
#pragma unroll
        for (int qf = 0; qf < 4; ++qf) {
            bf16x8 aq0 = fragRow(Qcur, 16 * qf + lr, 8 * g);
            bf16x8 aq1 = fragRow(Qcur, 16 * qf + lr, 32 + 8 * g);
#pragma unroll
            for (int c2 = 0; c2 < 4; ++c2) {
                f32x4 s = {0.f, 0.f, 0.f, 0.f};
                s = __builtin_amdgcn_mfma_f32_16x16x32_bf16(aq0, bk[c2][0], s, 0, 0, 0);
                s = __builtin_amdgcn_mfma_f32_16x16x32_bf16(aq1, bk[c2][1], s, 0, 0, 0);
#pragma unroll
                for (int rr = 0; rr < 4; ++rr)
                    zacc[c2][rr] += fexp2(s[rr]);
            }
        }
        __builtin_amdgcn_s_setprio(0);
        if (pre) { WAITV2; } else { WAITV0; }
        bar();
        cur = (cur + 1) & 3;
    }
#pragma unroll
    for (int c2 = 0; c2 < 4; ++c2) {
        float z = zacc[c2][0] + zacc[c2][1] + zacc[c2][2] + zacc[c2][3];
        z += __shfl_xor(z, 16);
        z += __shfl_xor(z, 32);
        if (l < 16)
            izOut[(size_t)bh * SS + k0 + 64 * w + 16 * c2 + l] = 1.f / z;
    }
}

// ---------------- ctx: 512-thread blocks (8 waves, 32 q-cols/wave), q-tile 256 ----------------
// R13's ctx was latency-bound at 8 waves/CU (2/SIMD). Same block tile + double the waves:
// per-block traffic unchanged (R11's mistake avoided), per-wave live set SHRINKS (~90 regs).
// (512,4) caps VGPR at 128 (headroom over natural ~90) and guarantees 2 blocks/CU.
__global__ __launch_bounds__(512, 4) void ctx_mfma(const short* __restrict__ qs,
                                                   const short* __restrict__ kh,
                                                   const short* __restrict__ vP,
                                                   const float* __restrict__ izArr,
                                                   short* __restrict__ ctxc) {
    __shared__ short LDS[24576];       // 48 KB: K[b]=LDS+b*4096 shorts (b<3), V[b]=LDS+12288+b*4096
    const int bid = blockIdx.x;
    const int r = bid & 63;
    const int bh = ((r & 7) << 3) | (r >> 3);
    const int q0 = (bid >> 6) * 256;
    const int b = bh >> 3, h = bh & 7;
    const int t = threadIdx.x;         // 0..511
    const int l = t & 63, w = t >> 6;  // w 0..7
    const int lr = l & 15, g = l >> 4;
    const short* Qb = qs + ((size_t)bh * SS + q0) * DK;
    const short* Kb = kh + (size_t)bh * SS * DK;
    const short* Vb = vP + (size_t)bh * DK * SS;
    const float* zB = izArr + (size_t)bh * SS;

    // stage Q tile [256][64] (32 KB worth of chunks over first 16K shorts? no: 2048 chunks) into region
#pragma unroll
    for (int p = 0; p < 4; ++p) {
        int c = p * 512 + t;
        int row = c >> 3, slot = c & 7;
        gld16(LDS + (size_t)(p * 512 + w * 64) * 8,
              Qb + (size_t)row * DK + ((slot ^ (row & 7)) * 8));
    }
    WAITV0;
    bar();
    bf16x8 qfr[2][2];                  // wave's 32 q-cols
#pragma unroll
    for (int qf = 0; qf < 2; ++qf)
#pragma unroll
        for (int c = 0; c < 2; ++c)
            qfr[qf][c] = fragRow(LDS, 32 * w + 16 * qf + lr, 32 * c + 8 * g);
    WAITL0;
    SCHED0;
    bar();                             // Q region now recyclable as KV buffers

    auto stageKV = [&](int buf, int kk) {
        {   // K tile 64x64 = 512 chunks, one pass of 512 threads
            int row = t >> 3, slot = t & 7;
            gld16(LDS + buf * 4096 + (size_t)(w * 64) * 8,
                  Kb + (size_t)(kk + row) * DK + ((slot ^ (row & 7)) * 8));
        }
        {
            int row = t >> 3, slot = t & 7;
            gld16(LDS + 12288 + buf * 4096 + (size_t)(w * 64) * 8,
                  Vb + (size_t)row * SS + kk + ((slot ^ (row & 7)) * 8));
        }
    };
    stageKV(0, 0);
    stageKV(1, 64);
    WAITV2;                            // KV0 landed; KV1 (2 loads) in flight
    bar();

    f32x4 acc[2][4];
#pragma unroll
    for (int a = 0; a < 2; ++a)
#pragma unroll
        for (int b2 = 0; b2 < 4; ++b2) acc[a][b2] = (f32x4){0.f, 0.f, 0.f, 0.f};

    int cur = 0;
    for (int it = 0; it < 32; ++it) {
        const int k0 = it * 64;
        const bool pre = (it < 30);
        // z loads for THIS iter, issued before the stage (oldest-first retirement)
        f32x4 z4[4];
#pragma unroll
        for (int kf = 0; kf < 4; ++kf)
            z4[kf] = *(const f32x4*)(zB + k0 + 16 * kf + 4 * g);
        SCHED0;
        if (pre) {
            int nb = cur + 2; if (nb >= 3) nb -= 3;
            stageKV(nb, k0 + 128);
        }
        const short* Kcur = LDS + cur * 4096;
        const short* Vcur = LDS + 12288 + cur * 4096;
        __builtin_amdgcn_s_setprio(1);
        bf16x8 Kf[4][2];
#pragma unroll
        for (int kf = 0; kf < 4; ++kf) {
            Kf[kf][0] = fragRow(Kcur, 16 * kf + lr, 8 * g);
            Kf[kf][1] = fragRow(Kcur, 16 * kf + lr, 32 + 8 * g);
        }
        // S phase: swapped mfma(K,Q) -> lane owns k=16kf+4g+rr for q=32w+16qf+lr
        bf16x8 pa[2][2];
#pragma unroll
        for (int qf = 0; qf < 2; ++qf) {
            float pw[4][4];
#pragma unroll
            for (int kf = 0; kf < 4; ++kf) {
                f32x4 s = {0.f, 0.f, 0.f, 0.f};
                s = __builtin_amdgcn_mfma_f32_16x16x32_bf16(Kf[kf][0], qfr[qf][0], s, 0, 0, 0);
                s = __builtin_amdgcn_mfma_f32_16x16x32_bf16(Kf[kf][1], qfr[qf][1], s, 0, 0, 0);
#pragma unroll
                for (int rr = 0; rr < 4; ++rr)
                    pw[kf][rr] = fexp2(s[rr]) * z4[kf][rr];
            }
#pragma unroll
            for (int c = 0; c < 2; ++c)
#pragma unroll
                for (int e = 0; e < 4; ++e) {
                    pa[qf][c][e]     = f2bf(pw[2 * c][e]);
                    pa[qf][c][4 + e] = f2bf(pw[2 * c + 1][e]);
                }
        }
        // PV: V pre-permuted in global -> standard swizzled frag read
#pragma unroll
        for (int vf = 0; vf < 4; ++vf)
#pragma unroll
            for (int c = 0; c < 2; ++c) {
                bf16x8 bv2 = fragRow(Vcur, 16 * vf + lr, 32 * c + 8 * g);
#pragma unroll
                for (int qf = 0; qf < 2; ++qf)
                    acc[qf][vf] = __builtin_amdgcn_mfma_f32_16x16x32_bf16(pa[qf][c], bv2, acc[qf][vf], 0, 0, 0);
            }
        __builtin_amdgcn_s_setprio(0);
        if (pre) { WAITV2; } else { WAITV0; }
        bar();
        cur = (cur == 2) ? 0 : cur + 1;
    }
    // bf16 concat-layout write [b, s, h*64+v]
    short* Cb = ctxc + ((size_t)b * SS + q0) * (HH * DK) + h * DK;
#pragma unroll
    for (int qf = 0; qf < 2; ++qf)
#pragma unroll
        for (int vf = 0; vf < 4; ++vf)
#pragma unroll
            for (int rr = 0; rr < 4; ++rr)
                Cb[(size_t)(32 * w + 16 * qf + 4 * g + rr) * (HH * DK) + 16 * vf + lr] =
                    f2bf(acc[qf][vf][rr]);
}

// ---------------- output projection: [16384x512]bf16 @ WoT + bo -> fp32, 2-phase ----------------
__global__ __launch_bounds__(256) void out_mfma(const short* __restrict__ A,
                                                const short* __restrict__ BT,
                                                const float* __restrict__ bo,
                                                float* __restrict__ out) {
    __shared__ short As[2][128 * 64];
    __shared__ short Bs[2][128 * 64];
    const int r0 = blockIdx.x * 128;
    const int j0 = blockIdx.y * 128;
    const int t = threadIdx.x;
    const int l = t & 63, w = t >> 6;
    const int lr = l & 15, g = l >> 4;
    const int wr = w >> 1, wc = w & 1;
    f32x4 acc[4][4];
#pragma unroll
    for (int i = 0; i < 4; ++i)
#pragma unroll
        for (int j = 0; j < 4; ++j) acc[i][j] = (f32x4){0.f, 0.f, 0.f, 0.f};

    auto stage = [&](int buf, int k0) {
#pragma unroll
        for (int p = 0; p < 4; ++p) {
            int c = p * 256 + w * 64 + l;
            int row = c >> 3, slot = c & 7;
            gld16(As[buf] + (size_t)(p * 256 + w * 64) * 8,
                  A + (size_t)(r0 + row) * DM + k0 + ((slot ^ (row & 7)) * 8));
            gld16(Bs[buf] + (size_t)(p * 256 + w * 64) * 8,
                  BT + (size_t)(j0 + row) * DM + k0 + ((slot ^ (row & 7)) * 8));
        }
    };
    stage(0, 0);
    WAITV0;
    __syncthreads();
    int cur = 0;
    for (int k0 = 0; k0 < DM; k0 += 64) {
        if (k0 + 64 < DM) stage(cur ^ 1, k0 + 64);
        bf16x8 bfr[4][2];
#pragma unroll
        for (int bf = 0; bf < 4; ++bf) {
            bfr[bf][0] = fragRow(Bs[cur], 64 * wc + 16 * bf + lr, 8 * g);
            bfr[bf][1] = fragRow(Bs[cur], 64 * wc + 16 * bf + lr, 32 + 8 * g);
        }
#pragma unroll
        for (int af = 0; af < 4; ++af) {
            bf16x8 a0 = fragRow(As[cur], 64 * wr + 16 * af + lr, 8 * g);
            bf16x8 a1 = fragRow(As[cur], 64 * wr + 16 * af + lr, 32 + 8 * g);
#pragma unroll
            for (int bf = 0; bf < 4; ++bf) {
                acc[af][bf] = __builtin_amdgcn_mfma_f32_16x16x32_bf16(a0, bfr[bf][0], acc[af][bf], 0, 0, 0);
                acc[af][bf] = __builtin_amdgcn_mfma_f32_16x16x32_bf16(a1, bfr[bf][1], acc[af][bf], 0, 0, 0);
            }
        }
        __syncthreads();
        cur ^= 1;
    }
#pragma unroll
    for (int af = 0; af < 4; ++af)
#pragma unroll
        for (int bf = 0; bf < 4; ++bf) {
            int j = j0 + 64 * wc + 16 * bf + lr;
            float bv2 = bo[j];
#pragma unroll
            for (int rr = 0; rr < 4; ++rr)
                out[(size_t)(r0 + 64 * wr + 16 * af + 4 * g + rr) * DM + j] = acc[af][bf][rr] + bv2;
        }
}

extern "C" void kernel_launch(void* const* d_in, const int* in_sizes, int n_in,
                              void* d_out, int out_size, void* d_ws, size_t ws_size,
                              hipStream_t stream) {
    const float* q  = (const float*)d_in[0];
    const float* k  = (const float*)d_in[1];
    const float* v  = (const float*)d_in[2];
    const float* Wq = (const float*)d_in[3];
    const float* bq = (const float*)d_in[4];
    const float* Wk = (const float*)d_in[5];
    const float* bk = (const float*)d_in[6];
    const float* Wv = (const float*)d_in[7];
    const float* bv = (const float*)d_in[8];
    const float* Wo = (const float*)d_in[9];
    const float* bo = (const float*)d_in[10];
    float* out = (float*)d_out;

    short* w16 = (short*)d_ws;
    const size_t NH = (size_t)BB * HH * SS * DK;  // 8,388,608
    const size_t NW = (size_t)HH * DM * DK;       // 262,144
    short* WqT = w16;
    short* WkT = WqT + NW;
    short* WvT = WkT + NW;
    short* WoT = WvT + NW;
    short* qsb = WoT + NW;
    short* khb = qsb + NH;
    short* vtb = khb + NH;
    short* ctc = vtb + NH;
    float* izb = (float*)(ctc + NH);

    const float qscale = 0.125f * 1.4426950408889634f;   // fold 1/sqrt(dk) and log2e

    dim3 blk(256);
    tcvtAll<<<dim3(8, 1, 32), blk, 0, stream>>>(Wq, Wk, Wv, Wo, WqT, WkT, WvT, WoT);
    proj_mfma<<<dim3(1024, 3), blk, 0, stream>>>(q, k, v, WqT, WkT, WvT, bq, bk, bv,
                                                 qsb, khb, vtb, qscale);
    stats_mfma<<<dim3(512), blk, 0, stream>>>(qsb, khb, izb);
    ctx_mfma<<<dim3(512), dim3(512), 0, stream>>>(qsb, khb, vtb, izb, ctc);
    out_mfma<<<dim3(128, 4), blk, 0, stream>>>(ctc, WoT, bo, out);
}

// Round 15
// 177.193 us; speedup vs baseline: 1.0866x; 1.0866x over previous
//
#include <hip/hip_runtime.h>
#include <hip/hip_bf16.h>
#include <math.h>

#define BB 8
#define SS 2048
#define HH 8
#define DM 512
#define DK 64

typedef short bf16x8 __attribute__((ext_vector_type(8)));
typedef float f32x4 __attribute__((ext_vector_type(4)));

static __device__ __forceinline__ short f2bf(float f) {
    union { __hip_bfloat16 h; short s; } u;
    u.h = __float2bfloat16(f);
    return u.s;
}

// exp2 (v_exp_f32); Q pre-scaled by 0.125*log2e so 2^s == e^(s/8)
static __device__ __forceinline__ float fexp2(float x) {
#if __has_builtin(__builtin_amdgcn_exp2f)
    return __builtin_amdgcn_exp2f(x);
#else
    return __expf(x * 0.69314718056f);
#endif
}

// async 16B global->LDS; LDS dest wave-uniform base + lane*16 implicit
static __device__ __forceinline__ void gld16(void* lds, const void* g) {
    __builtin_amdgcn_global_load_lds((const __attribute__((address_space(1))) void*)g,
                                     (__attribute__((address_space(3))) void*)lds, 16, 0, 0);
}

// swizzled read of 8 shorts from a [rows][64]-short LDS tile: 16B slot ^= (row&7)
static __device__ __forceinline__ bf16x8 fragRow(const short* lds, int row, int cshort) {
    return *(const bf16x8*)(lds + row * 64 + (cshort ^ ((row & 7) << 3)));
}

// raw barrier + scheduler fence (prevents ds ops drifting across the barrier)
static __device__ __forceinline__ void bar() {
    __builtin_amdgcn_s_barrier();
    __builtin_amdgcn_sched_barrier(0);
}
#define WAITV4 asm volatile("s_waitcnt vmcnt(4)" ::: "memory")
#define WAITV2 asm volatile("s_waitcnt vmcnt(2)" ::: "memory")
#define WAITV0 asm volatile("s_waitcnt vmcnt(0)" ::: "memory")
#define WAITL0 asm volatile("s_waitcnt lgkmcnt(0)" ::: "memory")
#define SCHED0 __builtin_amdgcn_sched_barrier(0)

// ---------------- merged transpose-convert: Wq/Wk/Wv (z<24) and Wo (z in [24,32)) ----------------
__global__ __launch_bounds__(256) void tcvtAll(const float* __restrict__ Wq, const float* __restrict__ Wk,
                                               const float* __restrict__ Wv, const float* __restrict__ Wo,
                                               short* __restrict__ WqT, short* __restrict__ WkT,
                                               short* __restrict__ WvT, short* __restrict__ WoT) {
    __shared__ short T[64][72];
    const int z = blockIdx.z;
    const int t = threadIdx.x;
    const int r0 = blockIdx.x * 64;
    const float* src;
    short* dst;
    int C, R, c0;
    if (z < 24) {
        const int which = z >> 3, h = z & 7;
        src = (which == 0 ? Wq : (which == 1 ? Wk : Wv)) + (size_t)h * DM * DK;
        dst = (which == 0 ? WqT : (which == 1 ? WkT : WvT)) + (size_t)h * DK * DM;
        C = DK; R = DM; c0 = 0;
    } else {
        src = Wo; dst = WoT;
        C = DM; R = DM; c0 = (z - 24) * 64;
    }
#pragma unroll
    for (int p = 0; p < 4; ++p) {
        int idx = t + 256 * p;
        int row = idx >> 4, c4 = (idx & 15) * 4;
        float4 v = *(const float4*)(src + (size_t)(r0 + row) * C + c0 + c4);
        T[c4 + 0][row] = f2bf(v.x);
        T[c4 + 1][row] = f2bf(v.y);
        T[c4 + 2][row] = f2bf(v.z);
        T[c4 + 3][row] = f2bf(v.w);
    }
    __syncthreads();
#pragma unroll
    for (int p = 0; p < 2; ++p) {
        int idx = t + 256 * p;
        int row = idx >> 3, slot = idx & 7;
        *(bf16x8*)(dst + (size_t)(c0 + row) * R + r0 + slot * 8) = *(const bf16x8*)&T[row][slot * 8];
    }
}

// ---------------- merged Q/K/V projection: fp32 X (reg-staged+cvt) @ bf16 WT ----------------
// Single-As-buffer T14 split; LDS 32 KB. launch_bounds (256,4): VGPR cap 128 fits the
// ~68-reg live set — (256,5)'s ~102 cap spilled ra[] to scratch (R9: 300MB writes).
__global__ __launch_bounds__(256, 4) void proj_mfma(const float* __restrict__ qX,
                                                    const float* __restrict__ kX,
                                                    const float* __restrict__ vX,
                                                    const short* __restrict__ WqT,
                                                    const short* __restrict__ WkT,
                                                    const short* __restrict__ WvT,
                                                    const float* __restrict__ bq,
                                                    const float* __restrict__ bk,
                                                    const float* __restrict__ bv,
                                                    short* __restrict__ qY,
                                                    short* __restrict__ kY,
                                                    short* __restrict__ vY,
                                                    float qscale) {
    __shared__ short As[128 * 64];     // 16 KB, single buffer
    __shared__ short Bs[2][64 * 64];   // 16 KB dbuf
    const int mode = blockIdx.y;
    const float* X = mode == 0 ? qX : (mode == 1 ? kX : vX);
    const short* WT = mode == 0 ? WqT : (mode == 1 ? WkT : WvT);
    const float* bias = mode == 0 ? bq : (mode == 1 ? bk : bv);
    short* Y = mode == 0 ? qY : (mode == 1 ? kY : vY);
    const float scale = mode == 0 ? qscale : 1.0f;

    const int lin = blockIdx.x;
    const int b = lin & 7, h = (lin >> 3) & 7;      // same-b blocks share an XCD's L2
    const int s0 = (lin >> 6) * 128;
    const int bh = b * 8 + h;
    const int t = threadIdx.x;
    const int l = t & 63, w = t >> 6;
    const int lr = l & 15, g = l >> 4;
    const float* Xb = X + ((size_t)b * SS + s0) * DM;
    const short* Wh = WT + (size_t)h * DK * DM;
    f32x4 acc[2][4];
#pragma unroll
    for (int i = 0; i < 2; ++i)
#pragma unroll
        for (int j = 0; j < 4; ++j) acc[i][j] = (f32x4){0.f, 0.f, 0.f, 0.f};

    float4 ra[8];
    auto loadA = [&](int k0) {
#pragma unroll
        for (int p = 0; p < 4; ++p) {
            int c = p * 256 + t;
            int row = c >> 3, col = (c & 7) * 8;
            ra[2 * p]     = *(const float4*)(Xb + (size_t)row * DM + k0 + col);
            ra[2 * p + 1] = *(const float4*)(Xb + (size_t)row * DM + k0 + col + 4);
        }
    };
    auto writeA = [&]() {
#pragma unroll
        for (int p = 0; p < 4; ++p) {
            int c = p * 256 + t;
            int row = c >> 3, slot = c & 7;
            bf16x8 o;
            o[0] = f2bf(ra[2 * p].x); o[1] = f2bf(ra[2 * p].y);
            o[2] = f2bf(ra[2 * p].z); o[3] = f2bf(ra[2 * p].w);
            o[4] = f2bf(ra[2 * p + 1].x); o[5] = f2bf(ra[2 * p + 1].y);
            o[6] = f2bf(ra[2 * p + 1].z); o[7] = f2bf(ra[2 * p + 1].w);
            *(bf16x8*)(As + row * 64 + ((slot ^ (row & 7)) * 8)) = o;
        }
    };
    auto stageB = [&](int buf, int k0) {
#pragma unroll
        for (int p = 0; p < 2; ++p) {
            int c = p * 256 + w * 64 + l;
            int row = c >> 3, slot = c & 7;
            gld16(Bs[buf] + (size_t)(p * 256 + w * 64) * 8,
                  Wh + (size_t)row * DM + k0 + ((slot ^ (row & 7)) * 8));
        }
    };

    loadA(0);            // oldest in queue
    stageB(0, 0);        // newest
    writeA();            // compiler waits vmcnt for ra only (B stays in flight)
    __syncthreads();     // drains vmcnt0 + lgkm, As/B0 visible
    int cur = 0;
    for (int k0 = 0; k0 < DM; k0 += 64) {
        const bool next = (k0 + 64 < DM);
        if (next) { loadA(k0 + 64); stageB(cur ^ 1, k0 + 64); }   // issue early (T14)
        SCHED0;
        bf16x8 bfr[4][2];
#pragma unroll
        for (int bf = 0; bf < 4; ++bf) {
            bfr[bf][0] = fragRow(Bs[cur], 16 * bf + lr, 8 * g);
            bfr[bf][1] = fragRow(Bs[cur], 16 * bf + lr, 32 + 8 * g);
        }
#pragma unroll
        for (int af = 0; af < 2; ++af) {
            bf16x8 a0 = fragRow(As, 32 * w + 16 * af + lr, 8 * g);
            bf16x8 a1 = fragRow(As, 32 * w + 16 * af + lr, 32 + 8 * g);
#pragma unroll
            for (int bf = 0; bf < 4; ++bf) {
                acc[af][bf] = __builtin_amdgcn_mfma_f32_16x16x32_bf16(a0, bfr[bf][0], acc[af][bf], 0, 0, 0);
                acc[af][bf] = __builtin_amdgcn_mfma_f32_16x16x32_bf16(a1, bfr[bf][1], acc[af][bf], 0, 0, 0);
            }
        }
        if (next) {
            bar();          // all waves finished READING As (ds_reads already waited)
            writeA();       // overwrite As with next tile (vmcnt wait leaves B in flight)
            __syncthreads();// drain vmcnt0+lgkm: As + Bs[cur^1] ready
        }
        cur ^= 1;
    }
    if (mode == 2) {
        // V^T with within-32 k-permutation: offset 16qf+4g+r stored at 8g+4qf+r
        short* Yb = Y + (size_t)bh * DK * SS;
#pragma unroll
        for (int qf = 0; qf < 2; ++qf)
#pragma unroll
            for (int nf = 0; nf < 4; ++nf) {
                int n = 16 * nf + lr;
                float bv2 = bias[h * DK + n];
                short4 o;
                o.x = f2bf(acc[qf][nf][0] + bv2);
                o.y = f2bf(acc[qf][nf][1] + bv2);
                o.z = f2bf(acc[qf][nf][2] + bv2);
                o.w = f2bf(acc[qf][nf][3] + bv2);
                *(short4*)(Yb + (size_t)n * SS + s0 + 32 * w + 8 * g + 4 * qf) = o;
            }
    } else {
        short* Yb = Y + ((size_t)bh * SS + s0) * DK;
#pragma unroll
        for (int qf = 0; qf < 2; ++qf)
#pragma unroll
            for (int nf = 0; nf < 4; ++nf) {
                int n = 16 * nf + lr;
                float bv2 = bias[h * DK + n];
#pragma unroll
                for (int r = 0; r < 4; ++r)
                    Yb[(size_t)(32 * w + 16 * qf + 4 * g + r) * DK + n] =
                        f2bf((acc[qf][nf][r] + bv2) * scale);
            }
    }
}

// ---------------- stats: l2iz[k] = -log2( sum_q 2^s' ); LDS union; (256,4) ----------------
__global__ __launch_bounds__(256, 4) void stats_mfma(const short* __restrict__ qs,
                                                     const short* __restrict__ kh,
                                                     float* __restrict__ l2izOut) {
    __shared__ short LDS[16384];       // 32 KB: K tile first, then 4x 8KB Q buffers
    const int bid = blockIdx.x;
    const int r = bid & 63;
    const int bh = ((r & 7) << 3) | (r >> 3);   // same-bh blocks share an XCD
    const int k0 = (bid >> 6) * 256;
    const int t = threadIdx.x;
    const int l = t & 63, w = t >> 6;
    const int lr = l & 15, g = l >> 4;
    const short* Qb = qs + (size_t)bh * SS * DK;
    const short* Kb = kh + ((size_t)bh * SS + k0) * DK;

    // stage K tile [256][64] into the full region
#pragma unroll
    for (int p = 0; p < 8; ++p) {
        int c = p * 256 + w * 64 + l;
        int row = c >> 3, slot = c & 7;
        gld16(LDS + (size_t)(p * 256 + w * 64) * 8,
              Kb + (size_t)row * DK + ((slot ^ (row & 7)) * 8));
    }
    WAITV0;
    bar();
    bf16x8 bk[4][2];                   // hoist wave's 64 k-cols to registers
#pragma unroll
    for (int c2 = 0; c2 < 4; ++c2) {
        bk[c2][0] = fragRow(LDS, 64 * w + 16 * c2 + lr, 8 * g);
        bk[c2][1] = fragRow(LDS, 64 * w + 16 * c2 + lr, 32 + 8 * g);
    }
    WAITL0;
    SCHED0;
    bar();                             // K region now recyclable as Q buffers

    auto stageQ = [&](int buf, int qq) {
#pragma unroll
        for (int p = 0; p < 2; ++p) {
            int c = p * 256 + w * 64 + l;
            int row = c >> 3, slot = c & 7;
            gld16(LDS + buf * 4096 + (size_t)(p * 256 + w * 64) * 8,
                  Qb + (size_t)(qq + row) * DK + ((slot ^ (row & 7)) * 8));
        }
    };
    stageQ(0, 0);
    stageQ(1, 64);
    WAITV2;
    bar();

    f32x4 zacc[4];
#pragma unroll
    for (int c2 = 0; c2 < 4; ++c2) zacc[c2] = (f32x4){0.f, 0.f, 0.f, 0.f};

    int cur = 0;
    for (int it = 0; it < 32; ++it) {
        const bool pre = (it < 30);
        if (pre) stageQ((cur + 2) & 3, (it + 2) * 64);
        const short* Qcur = LDS + cur * 4096;
        __builtin_amdgcn_s_setprio(1);
#pragma unroll
        for (int qf = 0; qf < 4; ++qf) {
            bf16x8 aq0 = fragRow(Qcur, 16 * qf + lr, 8 * g);
            bf16x8 aq1 = fragRow(Qcur, 16 * qf + lr, 32 + 8 * g);
#pragma unroll
            for (int c2 = 0; c2 < 4; ++c2) {
                f32x4 s = {0.f, 0.f, 0.f, 0.f};
                s = __builtin_amdgcn_mfma_f32_16x16x32_bf16(aq0, bk[c2][0], s, 0, 0, 0);
                s = __builtin_amdgcn_mfma_f32_16x16x32_bf16(aq1, bk[c2][1], s, 0, 0, 0);
#pragma unroll
                for (int rr = 0; rr < 4; ++rr)
                    zacc[c2][rr] += fexp2(s[rr]);
            }
        }
        __builtin_amdgcn_s_setprio(0);
        if (pre) { WAITV2; } else { WAITV0; }
        bar();
        cur = (cur + 1) & 3;
    }
#pragma unroll
    for (int c2 = 0; c2 < 4; ++c2) {
        float z = zacc[c2][0] + zacc[c2][1] + zacc[c2][2] + zacc[c2][3];
        z += __shfl_xor(z, 16);
        z += __shfl_xor(z, 32);
        if (l < 16)
            l2izOut[(size_t)bh * SS + k0 + 64 * w + 16 * c2 + l] = -__log2f(z);
    }
}

// ---------------- ctx: R13 config + l2iz folded into MFMA accumulator init ----------------
// S accumulator starts at l2iz[k] (lane layout matches k=16kf+4g+rr), so P = exp2(s)
// directly — deletes the per-element post-exp multiply (~9% of VALU, 2nd-busiest pipe).
__global__ __launch_bounds__(256, 2) void ctx_mfma(const short* __restrict__ qs,
                                                   const short* __restrict__ kh,
                                                   const short* __restrict__ vP,
                                                   const float* __restrict__ l2izArr,
                                                   short* __restrict__ ctxc) {
    __shared__ short LDS[24576];       // 48 KB: K[b]=LDS+b*4096 shorts (b<3), V[b]=LDS+12288+b*4096
    const int bid = blockIdx.x;
    const int r = bid & 63;
    const int bh = ((r & 7) << 3) | (r >> 3);
    const int q0 = (bid >> 6) * 256;
    const int b = bh >> 3, h = bh & 7;
    const int t = threadIdx.x;
    const int l = t & 63, w = t >> 6;
    const int lr = l & 15, g = l >> 4;
    const short* Qb = qs + ((size_t)bh * SS + q0) * DK;
    const short* Kb = kh + (size_t)bh * SS * DK;
    const short* Vb = vP + (size_t)bh * DK * SS;
    const float* zB = l2izArr + (size_t)bh * SS;

    // stage Q tile [256][64] into first 32 KB of the region
#pragma unroll
    for (int p = 0; p < 8; ++p) {
        int c = p * 256 + w * 64 + l;
        int row = c >> 3, slot = c & 7;
        gld16(LDS + (size_t)(p * 256 + w * 64) * 8,
              Qb + (size_t)row * DK + ((slot ^ (row & 7)) * 8));
    }
    WAITV0;
    bar();
    bf16x8 qfr[4][2];                  // hoist wave's 64 q-cols
#pragma unroll
    for (int qf = 0; qf < 4; ++qf)
#pragma unroll
        for (int c = 0; c < 2; ++c)
            qfr[qf][c] = fragRow(LDS, 64 * w + 16 * qf + lr, 32 * c + 8 * g);
    WAITL0;
    SCHED0;
    bar();                             // Q region now recyclable as KV buffers

    auto stageKV = [&](int buf, int kk) {
#pragma unroll
        for (int p = 0; p < 2; ++p) {
            int c = p * 256 + w * 64 + l;
            int row = c >> 3, slot = c & 7;
            gld16(LDS + buf * 4096 + (size_t)(p * 256 + w * 64) * 8,
                  Kb + (size_t)(kk + row) * DK + ((slot ^ (row & 7)) * 8));
        }
#pragma unroll
        for (int p = 0; p < 2; ++p) {
            int c = p * 256 + w * 64 + l;
            int row = c >> 3, slot = c & 7;
            gld16(LDS + 12288 + buf * 4096 + (size_t)(p * 256 + w * 64) * 8,
                  Vb + (size_t)row * SS + kk + ((slot ^ (row & 7)) * 8));
        }
    };
    stageKV(0, 0);
    stageKV(1, 64);
    WAITV4;                            // KV0 landed; KV1 in flight
    bar();

    f32x4 acc[4][4];
#pragma unroll
    for (int a = 0; a < 4; ++a)
#pragma unroll
        for (int b2 = 0; b2 < 4; ++b2) acc[a][b2] = (f32x4){0.f, 0.f, 0.f, 0.f};

    int cur = 0;
    for (int it = 0; it < 32; ++it) {
        const int k0 = it * 64;
        const bool pre = (it < 30);
        // l2iz loads for THIS iter, issued before the stage (oldest-first retirement)
        f32x4 z4[4];
#pragma unroll
        for (int kf = 0; kf < 4; ++kf)
            z4[kf] = *(const f32x4*)(zB + k0 + 16 * kf + 4 * g);
        SCHED0;
        if (pre) {
            int nb = cur + 2; if (nb >= 3) nb -= 3;
            stageKV(nb, k0 + 128);
        }
        const short* Kcur = LDS + cur * 4096;
        const short* Vcur = LDS + 12288 + cur * 4096;
        __builtin_amdgcn_s_setprio(1);
        bf16x8 Kf[4][2];
#pragma unroll
        for (int kf = 0; kf < 4; ++kf) {
            Kf[kf][0] = fragRow(Kcur, 16 * kf + lr, 8 * g);
            Kf[kf][1] = fragRow(Kcur, 16 * kf + lr, 32 + 8 * g);
        }
        // S phase: swapped mfma(K,Q), ACC INIT = l2iz -> s already normalized in log2 domain
        bf16x8 pa[4][2];
#pragma unroll
        for (int qf = 0; qf < 4; ++qf) {
            float pw[4][4];
#pragma unroll
            for (int kf = 0; kf < 4; ++kf) {
                f32x4 s = z4[kf];
                s = __builtin_amdgcn_mfma_f32_16x16x32_bf16(Kf[kf][0], qfr[qf][0], s, 0, 0, 0);
                s = __builtin_amdgcn_mfma_f32_16x16x32_bf16(Kf[kf][1], qfr[qf][1], s, 0, 0, 0);
#pragma unroll
                for (int rr = 0; rr < 4; ++rr)
                    pw[kf][rr] = fexp2(s[rr]);
            }
#pragma unroll
            for (int c = 0; c < 2; ++c)
#pragma unroll
                for (int e = 0; e < 4; ++e) {
                    pa[qf][c][e]     = f2bf(pw[2 * c][e]);
                    pa[qf][c][4 + e] = f2bf(pw[2 * c + 1][e]);
                }
        }
        // PV: V pre-permuted in global -> standard swizzled frag read
#pragma unroll
        for (int vf = 0; vf < 4; ++vf)
#pragma unroll
            for (int c = 0; c < 2; ++c) {
                bf16x8 bv2 = fragRow(Vcur, 16 * vf + lr, 32 * c + 8 * g);
#pragma unroll
                for (int qf = 0; qf < 4; ++qf)
                    acc[qf][vf] = __builtin_amdgcn_mfma_f32_16x16x32_bf16(pa[qf][c], bv2, acc[qf][vf], 0, 0, 0);
            }
        __builtin_amdgcn_s_setprio(0);
        if (pre) { WAITV4; } else { WAITV0; }
        bar();
        cur = (cur == 2) ? 0 : cur + 1;
    }
    // bf16 concat-layout write [b, s, h*64+v]
    short* Cb = ctxc + ((size_t)b * SS + q0) * (HH * DK) + h * DK;
#pragma unroll
    for (int qf = 0; qf < 4; ++qf)
#pragma unroll
        for (int vf = 0; vf < 4; ++vf)
#pragma unroll
            for (int rr = 0; rr < 4; ++rr)
                Cb[(size_t)(64 * w + 16 * qf + 4 * g + rr) * (HH * DK) + 16 * vf + lr] =
                    f2bf(acc[qf][vf][rr]);
}

// ---------------- output projection: [16384x512]bf16 @ WoT + bo -> fp32, 2-phase ----------------
__global__ __launch_bounds__(256) void out_mfma(const short* __restrict__ A,
                                                const short* __restrict__ BT,
                                                const float* __restrict__ bo,
                                                float* __restrict__ out) {
    __shared__ short As[2][128 * 64];
    __shared__ short Bs[2][128 * 64];
    const int r0 = blockIdx.x * 128;
    const int j0 = blockIdx.y * 128;
    const int t = threadIdx.x;
    const int l = t & 63, w = t >> 6;
    const int lr = l & 15, g = l >> 4;
    const int wr = w >> 1, wc = w & 1;
    f32x4 acc[4][4];
#pragma unroll
    for (int i = 0; i < 4; ++i)
#pragma unroll
        for (int j = 0; j < 4; ++j) acc[i][j] = (f32x4){0.f, 0.f, 0.f, 0.f};

    auto stage = [&](int buf, int k0) {
#pragma unroll
        for (int p = 0; p < 4; ++p) {
            int c = p * 256 + w * 64 + l;
            int row = c >> 3, slot = c & 7;
            gld16(As[buf] + (size_t)(p * 256 + w * 64) * 8,
                  A + (size_t)(r0 + row) * DM + k0 + ((slot ^ (row & 7)) * 8));
            gld16(Bs[buf] + (size_t)(p * 256 + w * 64) * 8,
                  BT + (size_t)(j0 + row) * DM + k0 + ((slot ^ (row & 7)) * 8));
        }
    };
    stage(0, 0);
    WAITV0;
    __syncthreads();
    int cur = 0;
    for (int k0 = 0; k0 < DM; k0 += 64) {
        if (k0 + 64 < DM) stage(cur ^ 1, k0 + 64);
        bf16x8 bfr[4][2];
#pragma unroll
        for (int bf = 0; bf < 4; ++bf) {
            bfr[bf][0] = fragRow(Bs[cur], 64 * wc + 16 * bf + lr, 8 * g);
            bfr[bf][1] = fragRow(Bs[cur], 64 * wc + 16 * bf + lr, 32 + 8 * g);
        }
#pragma unroll
        for (int af = 0; af < 4; ++af) {
            bf16x8 a0 = fragRow(As[cur], 64 * wr + 16 * af + lr, 8 * g);
            bf16x8 a1 = fragRow(As[cur], 64 * wr + 16 * af + lr, 32 + 8 * g);
#pragma unroll
            for (int bf = 0; bf < 4; ++bf) {
                acc[af][bf] = __builtin_amdgcn_mfma_f32_16x16x32_bf16(a0, bfr[bf][0], acc[af][bf], 0, 0, 0);
                acc[af][bf] = __builtin_amdgcn_mfma_f32_16x16x32_bf16(a1, bfr[bf][1], acc[af][bf], 0, 0, 0);
            }
        }
        __syncthreads();
        cur ^= 1;
    }
#pragma unroll
    for (int af = 0; af < 4; ++af)
#pragma unroll
        for (int bf = 0; bf < 4; ++bf) {
            int j = j0 + 64 * wc + 16 * bf + lr;
            float bv2 = bo[j];
#pragma unroll
            for (int rr = 0; rr < 4; ++rr)
                out[(size_t)(r0 + 64 * wr + 16 * af + 4 * g + rr) * DM + j] = acc[af][bf][rr] + bv2;
        }
}

extern "C" void kernel_launch(void* const* d_in, const int* in_sizes, int n_in,
                              void* d_out, int out_size, void* d_ws, size_t ws_size,
                              hipStream_t stream) {
    const float* q  = (const float*)d_in[0];
    const float* k  = (const float*)d_in[1];
    const float* v  = (const float*)d_in[2];
    const float* Wq = (const float*)d_in[3];
    const float* bq = (const float*)d_in[4];
    const float* Wk = (const float*)d_in[5];
    const float* bk = (const float*)d_in[6];
    const float* Wv = (const float*)d_in[7];
    const float* bv = (const float*)d_in[8];
    const float* Wo = (const float*)d_in[9];
    const float* bo = (const float*)d_in[10];
    float* out = (float*)d_out;

    short* w16 = (short*)d_ws;
    const size_t NH = (size_t)BB * HH * SS * DK;  // 8,388,608
    const size_t NW = (size_t)HH * DM * DK;       // 262,144
    short* WqT = w16;
    short* WkT = WqT + NW;
    short* WvT = WkT + NW;
    short* WoT = WvT + NW;
    short* qsb = WoT + NW;
    short* khb = qsb + NH;
    short* vtb = khb + NH;
    short* ctc = vtb + NH;
    float* izb = (float*)(ctc + NH);

    const float qscale = 0.125f * 1.4426950408889634f;   // fold 1/sqrt(dk) and log2e

    dim3 blk(256);
    tcvtAll<<<dim3(8, 1, 32), blk, 0, stream>>>(Wq, Wk, Wv, Wo, WqT, WkT, WvT, WoT);
    proj_mfma<<<dim3(1024, 3), blk, 0, stream>>>(q, k, v, WqT, WkT, WvT, bq, bk, bv,
                                                 qsb, khb, vtb, qscale);
    stats_mfma<<<dim3(512), blk, 0, stream>>>(qsb, khb, izb);
    ctx_mfma<<<dim3(512), blk, 0, stream>>>(qsb, khb, vtb, izb, ctc);
    out_mfma<<<dim3(128, 4), blk, 0, stream>>>(ctc, WoT, bo, out);
}